// Round 7
// baseline (359.191 us; speedup 1.0000x reference)
//
#include <hip/hip_runtime.h>
#include <stdint.h>

#define N_ROWS 500000
#define Q0 50000
#define Q1 10000
#define NB (Q0 + Q1)
#define NTILES (N_ROWS / 16)          // 31250 exactly

// ---- partition geometry ----
#define SH0T 9                        // table0: 512-bucket partitions
#define SH1T 8                        // table1: 256-bucket partitions
#define NP0 98                        // ceil(50000/512)
#define NP1 40                        // ceil(10000/256)
#define NPARTS (NP0 + NP1)
#define TILE_ROWS 1024
#define T_TILES ((N_ROWS + TILE_ROWS - 1) / TILE_ROWS)   // 489 per table

typedef __attribute__((ext_vector_type(8))) short bf16x8;   // 8 bf16 (4 VGPRs)
typedef __attribute__((ext_vector_type(4))) float f32x4;

static __device__ __forceinline__ uint32_t f2bfu(float f) {
    uint32_t u = __builtin_bit_cast(uint32_t, f);
    u += 0x7fffu + ((u >> 16) & 1u);          // round-to-nearest-even
    return u >> 16;
}
static __device__ __forceinline__ short f2bf(float f) { return (short)f2bfu(f); }
static __device__ __forceinline__ float bfu2f(uint32_t u) {
    return __builtin_bit_cast(float, u << 16);
}
static __device__ __forceinline__ uint32_t pk2(float x, float y) {
    return f2bfu(x) | (f2bfu(y) << 16);
}

__global__ __launch_bounds__(256) void zero_ws_kernel(uint32_t* __restrict__ p, int total) {
    int stride = gridDim.x * 256;
    for (int i = blockIdx.x * 256 + threadIdx.x; i < total; i += stride) p[i] = 0u;
}

// Pass A: partition-scatter with LDS staging -> coalesced global runs.
// Blocks [0,489) handle table0 tiles; [489,978) table1 tiles.
__global__ __launch_bounds__(256) void partA_kernel(const int* __restrict__ z0,
                                                    const int* __restrict__ z1,
                                                    const float* __restrict__ emb0,
                                                    const float* __restrict__ emb1,
                                                    uint32_t* __restrict__ pid0,
                                                    uint32_t* __restrict__ pdata0,
                                                    uint32_t* __restrict__ pid1,
                                                    uint32_t* __restrict__ pdata1,
                                                    int* __restrict__ curs,
                                                    int* __restrict__ ovfcnt,
                                                    float* __restrict__ ovf,
                                                    int cap0, int cap1) {
    const bool is0 = blockIdx.x < T_TILES;
    const int tile = is0 ? blockIdx.x : blockIdx.x - T_TILES;
    const int* z = is0 ? z0 : z1;
    const float* emb = is0 ? emb0 : emb1;
    const int nparts = is0 ? NP0 : NP1;
    const int SH = is0 ? SH0T : SH1T;
    const int cap = is0 ? cap0 : cap1;
    uint32_t* pid = is0 ? pid0 : pid1;
    uint32_t* pdata = is0 ? pdata0 : pdata1;
    int* cur = curs + (is0 ? 0 : NP0);
    const int wofs = is0 ? 0 : Q0;

    __shared__ int lcnt[NP0];
    __shared__ int loff[NP0 + 1];
    __shared__ int gbase[NP0];
    __shared__ uint32_t sid[TILE_ROWS];
    __shared__ uint32_t spay[TILE_ROWS * 8];      // 32 KB

    const int t = threadIdx.x;
    for (int i = t; i < nparts; i += 256) lcnt[i] = 0;
    __syncthreads();

    int bks[4], rnk[4];
    const int base = tile * TILE_ROWS;
#pragma unroll
    for (int i = 0; i < 4; i++) {
        int r = base + i * 256 + t;
        if (r < N_ROWS) {
            int b = z[r];
            bks[i] = b;
            rnk[i] = atomicAdd(&lcnt[b >> SH], 1);
        } else {
            bks[i] = -1;
            rnk[i] = 0;
        }
    }
    __syncthreads();
    if (t == 0) {
        int s = 0;
        for (int p = 0; p < nparts; p++) { loff[p] = s; s += lcnt[p]; }
        loff[nparts] = s;
    }
    __syncthreads();
    if (t < nparts) gbase[t] = atomicAdd(&cur[t], lcnt[t]);
    __syncthreads();

    // place entries (bf16 payload) partition-ordered in staging
#pragma unroll
    for (int i = 0; i < 4; i++) {
        if (bks[i] < 0) continue;
        int r = base + i * 256 + t;
        int p = bks[i] >> SH;
        int s = loff[p] + rnk[i];
        sid[s] = (uint32_t)bks[i];
        const float4* e = (const float4*)(emb + (size_t)r * 16);
        float4 A = e[0], B = e[1], C = e[2], D = e[3];
        uint32_t* d = &spay[s * 8];
        d[0] = pk2(A.x, A.y); d[1] = pk2(A.z, A.w);
        d[2] = pk2(B.x, B.y); d[3] = pk2(B.z, B.w);
        d[4] = pk2(C.x, C.y); d[5] = pk2(C.z, C.w);
        d[6] = pk2(D.x, D.y); d[7] = pk2(D.z, D.w);
    }
    __syncthreads();

    const int E = loff[nparts];
    // id copy (coalesced runs) + overflow counts
    for (int s = t; s < E; s += 256) {
        int b = (int)sid[s];
        int p = b >> SH;
        int dest = gbase[p] + (s - loff[p]);
        if (dest < cap) pid[(size_t)p * cap + dest] = (uint32_t)b;
        else atomicAdd(&ovfcnt[b + wofs], 1);
    }
    // payload copy (coalesced runs) + overflow sums
    for (int j = t; j < E * 8; j += 256) {
        int s = j >> 3, q = j & 7;
        int b = (int)sid[s];
        int p = b >> SH;
        int dest = gbase[p] + (s - loff[p]);
        uint32_t x = spay[j];
        if (dest < cap) {
            pdata[((size_t)p * cap + dest) * 8 + q] = x;
        } else {
            atomicAdd(&ovf[(size_t)(b + wofs) * 16 + q * 2],     bfu2f(x & 0xffffu));
            atomicAdd(&ovf[(size_t)(b + wofs) * 16 + q * 2 + 1], bfu2f(x >> 16));
        }
    }
}

// Pass B: one block per partition. Sequential entry read, LDS segment-sum,
// add overflow, divide_no_nan, coalesced means write.
__global__ __launch_bounds__(256) void partB_kernel(const uint32_t* __restrict__ pid0,
                                                    const uint32_t* __restrict__ pdata0,
                                                    const uint32_t* __restrict__ pid1,
                                                    const uint32_t* __restrict__ pdata1,
                                                    const int* __restrict__ curs,
                                                    const int* __restrict__ ovfcnt,
                                                    const float* __restrict__ ovf,
                                                    float* __restrict__ means,
                                                    int cap0, int cap1) {
    const int p = blockIdx.x;
    const bool is0 = p < NP0;
    const int lp = is0 ? p : p - NP0;
    const int SH = is0 ? SH0T : SH1T;
    const int NBK = 1 << SH;
    const int fb = lp << SH;                      // first bucket (table-local)
    const int wofs = is0 ? 0 : Q0;
    const int qmax = is0 ? Q0 : Q1;
    const int cap = is0 ? cap0 : cap1;
    const uint32_t* pi = (is0 ? pid0 : pid1) + (size_t)lp * cap;
    const uint32_t* pd = (is0 ? pdata0 : pdata1) + (size_t)lp * cap * 8;
    int n = curs[p];
    if (n > cap) n = cap;

    __shared__ float sums[512 * 16];              // 32 KB
    __shared__ int cnt[512];
    const int t = threadIdx.x;
    for (int i = t; i < NBK * 16; i += 256) sums[i] = 0.0f;
    for (int i = t; i < NBK; i += 256) cnt[i] = 0;
    __syncthreads();

    for (int j = t; j < n * 8; j += 256) {
        int s = j >> 3, q = j & 7;
        int lb = (int)pi[s] - fb;
        uint32_t x = pd[j];
        atomicAdd(&sums[lb * 16 + q * 2],     bfu2f(x & 0xffffu));
        atomicAdd(&sums[lb * 16 + q * 2 + 1], bfu2f(x >> 16));
        if (q == 0) atomicAdd(&cnt[lb], 1);
    }
    __syncthreads();

    for (int i = t; i < NBK * 16; i += 256) {
        int lb = i >> 4, d = i & 15;
        int b = fb + lb;
        if (b >= qmax) continue;
        int w = b + wofs;
        float c = (float)cnt[lb] + (float)ovfcnt[w];
        float s = sums[i] + ovf[(size_t)w * 16 + d];
        means[(size_t)w * 16 + d] = (c > 0.0f) ? (s / c) : 0.0f;   // divide_no_nan
    }
}

// Fused gather + 3-layer MLP using bf16 MFMA. One wave = one 16-row tile.
__global__ __launch_bounds__(256, 2) void mlp_mfma_kernel(
    const float* __restrict__ X, const int* __restrict__ z0, const int* __restrict__ z1,
    const float* __restrict__ means,
    const float* __restrict__ W1, const float* __restrict__ b1,
    const float* __restrict__ W2, const float* __restrict__ b2,
    const float* __restrict__ Wout, const float* __restrict__ bout,
    float* __restrict__ out)
{
    __shared__ float h1s[4][16 * 128];        // per-wave private transpose buffer (8 KB each)
    const int lane = threadIdx.x & 63;
    const int wv = threadIdx.x >> 6;
    const int c = lane & 15;                  // A-row / B-col / D-col index
    const int g = lane >> 4;                  // k-group
    float* h1w = h1s[wv];

    // ---- build B-fragments for W1 (8 col-tiles x 2 k-steps) and W2 (4 x 4) in registers
    bf16x8 w1f[8][2];
#pragma unroll
    for (int ct = 0; ct < 8; ct++)
#pragma unroll
        for (int ks = 0; ks < 2; ks++)
#pragma unroll
            for (int e = 0; e < 8; e++)
                w1f[ct][ks][e] = f2bf(W1[(ks * 32 + g * 8 + e) * 128 + ct * 16 + c]);

    bf16x8 w2f[4][4];
#pragma unroll
    for (int ct = 0; ct < 4; ct++)
#pragma unroll
        for (int ks = 0; ks < 4; ks++)
#pragma unroll
            for (int e = 0; e < 8; e++)
                w2f[ct][ks][e] = f2bf(W2[(ks * 32 + g * 8 + e) * 64 + ct * 16 + c]);

    float b1v[8], b2v[4], wo[4];
#pragma unroll
    for (int ct = 0; ct < 8; ct++) b1v[ct] = b1[ct * 16 + c];
#pragma unroll
    for (int ct = 0; ct < 4; ct++) b2v[ct] = b2[ct * 16 + c];
#pragma unroll
    for (int t = 0; t < 4; t++) wo[t] = Wout[t * 16 + c];
    const float bo = bout[0];

    // emb-gather routing for the k=32..63 fragment: g<2 -> mean0, g>=2 -> mean1
    const int gg = g * 8;
    const bool is0 = (gg < 16);
    const int* zp = is0 ? z0 : z1;
    const size_t moff = is0 ? 0 : (size_t)Q0 * 16;
    const int esub = gg & 8;

    // ---- swizzled LDS addressing (XOR bits 2-3 of dword index with row&3)
    int waddr[4];                             // write: rows g*4+r, col c (+ct*16 imm)
#pragma unroll
    for (int r = 0; r < 4; r++) {
        int rowl = g * 4 + r;
        waddr[r] = rowl * 128 + (c ^ ((rowl & 3) << 2));
    }
    const int xr = (c & 3) << 2;              // read: row c, feats g*8+e (+ks*32)
    const int lo0 = ((g & 1) << 3) ^ xr;
    const int rbase0 = c * 128 + ((g >> 1) << 4) + lo0;
    const int rbase1 = c * 128 + ((g >> 1) << 4) + (lo0 ^ 4);

    const int wave_id = blockIdx.x * 4 + wv;
    const int nw = gridDim.x * 4;

    for (int tile = wave_id; tile < NTILES; tile += nw) {
        const int row = tile * 16 + c;

        // ---- A1 fragments: k 0..31 from X, k 32..63 from the mean tables
        bf16x8 a1[2];
        const float4* xp = (const float4*)(X + (size_t)row * 32 + gg);
        float4 x0 = xp[0], x1 = xp[1];
        a1[0][0] = f2bf(x0.x); a1[0][1] = f2bf(x0.y);
        a1[0][2] = f2bf(x0.z); a1[0][3] = f2bf(x0.w);
        a1[0][4] = f2bf(x1.x); a1[0][5] = f2bf(x1.y);
        a1[0][6] = f2bf(x1.z); a1[0][7] = f2bf(x1.w);

        int a = zp[row];
        const float4* ep = (const float4*)(means + moff + (size_t)a * 16 + esub);
        float4 e0 = ep[0], e1 = ep[1];
        a1[1][0] = f2bf(e0.x); a1[1][1] = f2bf(e0.y);
        a1[1][2] = f2bf(e0.z); a1[1][3] = f2bf(e0.w);
        a1[1][4] = f2bf(e1.x); a1[1][5] = f2bf(e1.y);
        a1[1][6] = f2bf(e1.z); a1[1][7] = f2bf(e1.w);

        // ---- layer 1: D1[ct] = A1 @ W1[:, ct*16..+16] + b1
        f32x4 d1[8];
#pragma unroll
        for (int ct = 0; ct < 8; ct++) {
            f32x4 acc = {b1v[ct], b1v[ct], b1v[ct], b1v[ct]};
            acc = __builtin_amdgcn_mfma_f32_16x16x32_bf16(a1[0], w1f[ct][0], acc, 0, 0, 0);
            acc = __builtin_amdgcn_mfma_f32_16x16x32_bf16(a1[1], w1f[ct][1], acc, 0, 0, 0);
            d1[ct] = acc;
        }

        // ---- relu + transpose via swizzled LDS (wave-private, no barrier needed)
#pragma unroll
        for (int ct = 0; ct < 8; ct++)
#pragma unroll
            for (int r = 0; r < 4; r++)
                h1w[waddr[r] + ct * 16] = fmaxf(d1[ct][r], 0.0f);

        // ---- A2 fragments from LDS (2 x b128 per k-step, bank-floor-optimal)
        bf16x8 a2[4];
#pragma unroll
        for (int ks = 0; ks < 4; ks++) {
            f32x4 p0 = *(const f32x4*)&h1w[rbase0 + ks * 32];
            f32x4 p1 = *(const f32x4*)&h1w[rbase1 + ks * 32];
            a2[ks][0] = f2bf(p0[0]); a2[ks][1] = f2bf(p0[1]);
            a2[ks][2] = f2bf(p0[2]); a2[ks][3] = f2bf(p0[3]);
            a2[ks][4] = f2bf(p1[0]); a2[ks][5] = f2bf(p1[1]);
            a2[ks][6] = f2bf(p1[2]); a2[ks][7] = f2bf(p1[3]);
        }

        // ---- layer 2: D2[ct] = relu(h1) @ W2[:, ct*16..+16] + b2
        f32x4 d2[4];
#pragma unroll
        for (int ct = 0; ct < 4; ct++) {
            f32x4 acc = {b2v[ct], b2v[ct], b2v[ct], b2v[ct]};
#pragma unroll
            for (int ks = 0; ks < 4; ks++)
                acc = __builtin_amdgcn_mfma_f32_16x16x32_bf16(a2[ks], w2f[ct][ks], acc, 0, 0, 0);
            d2[ct] = acc;
        }

        // ---- layer 3 on VALU + 16-lane butterfly reduce + store
        float sr[4];
#pragma unroll
        for (int r = 0; r < 4; r++) {
            float s = 0.0f;
#pragma unroll
            for (int ct = 0; ct < 4; ct++)
                s = fmaf(fmaxf(d2[ct][r], 0.0f), wo[ct], s);
            sr[r] = s;
        }
#pragma unroll
        for (int m = 1; m <= 8; m <<= 1)
#pragma unroll
            for (int r = 0; r < 4; r++)
                sr[r] += __shfl_xor(sr[r], m);
        if (c == 0) {
            float4 o = {sr[0] + bo, sr[1] + bo, sr[2] + bo, sr[3] + bo};
            *(float4*)(out + tile * 16 + g * 4) = o;
        }
    }
}

extern "C" void kernel_launch(void* const* d_in, const int* in_sizes, int n_in,
                              void* d_out, int out_size, void* d_ws, size_t ws_size,
                              hipStream_t stream) {
    const float* X    = (const float*)d_in[0];
    const int*   z0   = (const int*)d_in[1];
    const int*   z1   = (const int*)d_in[2];
    const float* emb0 = (const float*)d_in[3];
    const float* emb1 = (const float*)d_in[4];
    const float* W1   = (const float*)d_in[5];
    const float* b1   = (const float*)d_in[6];
    const float* W2   = (const float*)d_in[7];
    const float* b2   = (const float*)d_in[8];
    const float* Wout = (const float*)d_in[9];
    const float* bout = (const float*)d_in[10];
    float* out = (float*)d_out;
    char* ws = (char*)d_ws;

    // fixed region: cursors + ovfcnt + ovf + means
    const size_t fixedB = (size_t)NPARTS * 4 + (size_t)NB * 4 + (size_t)NB * 64 * 2;
    // capacity ladder (deterministic host-side); overflow path keeps every rung correct
    const int c0s[4] = {8192, 6656, 5632, 0};
    const int c1s[4] = {16384, 14336, 13056, 0};
    int CAP0 = 0, CAP1 = 0;
    for (int i = 0; i < 4; i++) {
        size_t need = ((size_t)NP0 * c0s[i] + (size_t)NP1 * c1s[i]) * 36 + fixedB;
        if (need <= ws_size) { CAP0 = c0s[i]; CAP1 = c1s[i]; break; }
    }

    char* p = ws;
    uint32_t* pdata0 = (uint32_t*)p;  p += (size_t)NP0 * CAP0 * 32;
    uint32_t* pdata1 = (uint32_t*)p;  p += (size_t)NP1 * CAP1 * 32;
    uint32_t* pid0   = (uint32_t*)p;  p += (size_t)NP0 * CAP0 * 4;
    uint32_t* pid1   = (uint32_t*)p;  p += (size_t)NP1 * CAP1 * 4;
    uint32_t* zbase  = (uint32_t*)p;
    int* curs        = (int*)p;       p += (size_t)NPARTS * 4;
    int* ovfcnt      = (int*)p;       p += (size_t)NB * 4;
    float* ovf       = (float*)p;     p += (size_t)NB * 64;
    float* means     = (float*)p;

    const int zero_dwords = NPARTS + NB + NB * 16;
    zero_ws_kernel<<<1024, 256, 0, stream>>>(zbase, zero_dwords);
    partA_kernel<<<2 * T_TILES, 256, 0, stream>>>(z0, z1, emb0, emb1,
                                                  pid0, pdata0, pid1, pdata1,
                                                  curs, ovfcnt, ovf, CAP0, CAP1);
    partB_kernel<<<NPARTS, 256, 0, stream>>>(pid0, pdata0, pid1, pdata1,
                                             curs, ovfcnt, ovf, means, CAP0, CAP1);
    mlp_mfma_kernel<<<512, 256, 0, stream>>>(X, z0, z1, means, W1, b1, W2, b2,
                                             Wout, bout, out);
}

// Round 8
// 221.929 us; speedup vs baseline: 1.6185x; 1.6185x over previous
//
#include <hip/hip_runtime.h>
#include <stdint.h>

#define N_ROWS 500000
#define Q0 50000
#define Q1 10000
#define NB (Q0 + Q1)
#define NTILES (N_ROWS / 16)          // 31250 exactly

// ---- partition geometry ----
#define SH0T 9                        // table0: 512-bucket partitions
#define SH1T 8                        // table1: 256-bucket partitions
#define NP0 98                        // ceil(50000/512)
#define NP1 40                        // ceil(10000/256)
#define NPARTS (NP0 + NP1)
#define TILE_ROWS 1024
#define T_TILES ((N_ROWS + TILE_ROWS - 1) / TILE_ROWS)   // 489 per table

#define CHUNK 2048                    // entries per partB block
#define PSTRIDE (512 * 16 + 512)      // floats per partial block (sums + counts)

typedef __attribute__((ext_vector_type(8))) short bf16x8;   // 8 bf16 (4 VGPRs)
typedef __attribute__((ext_vector_type(4))) float f32x4;

static __device__ __forceinline__ uint32_t f2bfu(float f) {
    uint32_t u = __builtin_bit_cast(uint32_t, f);
    u += 0x7fffu + ((u >> 16) & 1u);          // round-to-nearest-even
    return u >> 16;
}
static __device__ __forceinline__ short f2bf(float f) { return (short)f2bfu(f); }
static __device__ __forceinline__ float bfu2f(uint32_t u) {
    return __builtin_bit_cast(float, u << 16);
}
static __device__ __forceinline__ uint32_t pk2(float x, float y) {
    return f2bfu(x) | (f2bfu(y) << 16);
}

__global__ __launch_bounds__(256) void zero_ws_kernel(uint32_t* __restrict__ p, int total) {
    int stride = gridDim.x * 256;
    for (int i = blockIdx.x * 256 + threadIdx.x; i < total; i += stride) p[i] = 0u;
}

// Pass A: partition-scatter with LDS staging -> coalesced global runs.
__global__ __launch_bounds__(256) void partA_kernel(const int* __restrict__ z0,
                                                    const int* __restrict__ z1,
                                                    const float* __restrict__ emb0,
                                                    const float* __restrict__ emb1,
                                                    uint32_t* __restrict__ pid0,
                                                    uint32_t* __restrict__ pdata0,
                                                    uint32_t* __restrict__ pid1,
                                                    uint32_t* __restrict__ pdata1,
                                                    int* __restrict__ curs,
                                                    int* __restrict__ ovfcnt,
                                                    float* __restrict__ ovf,
                                                    int cap0, int cap1) {
    const bool is0 = blockIdx.x < T_TILES;
    const int tile = is0 ? blockIdx.x : blockIdx.x - T_TILES;
    const int* z = is0 ? z0 : z1;
    const float* emb = is0 ? emb0 : emb1;
    const int nparts = is0 ? NP0 : NP1;
    const int SH = is0 ? SH0T : SH1T;
    const int cap = is0 ? cap0 : cap1;
    uint32_t* pid = is0 ? pid0 : pid1;
    uint32_t* pdata = is0 ? pdata0 : pdata1;
    int* cur = curs + (is0 ? 0 : NP0);
    const int wofs = is0 ? 0 : Q0;

    __shared__ int lcnt[NP0];
    __shared__ int loff[NP0 + 1];
    __shared__ int gbase[NP0];
    __shared__ uint32_t sid[TILE_ROWS];
    __shared__ uint32_t spay[TILE_ROWS * 8];      // 32 KB

    const int t = threadIdx.x;
    for (int i = t; i < nparts; i += 256) lcnt[i] = 0;
    __syncthreads();

    int bks[4], rnk[4];
    const int base = tile * TILE_ROWS;
#pragma unroll
    for (int i = 0; i < 4; i++) {
        int r = base + i * 256 + t;
        if (r < N_ROWS) {
            int b = z[r];
            bks[i] = b;
            rnk[i] = atomicAdd(&lcnt[b >> SH], 1);
        } else {
            bks[i] = -1;
            rnk[i] = 0;
        }
    }
    __syncthreads();
    if (t == 0) {
        int s = 0;
        for (int p = 0; p < nparts; p++) { loff[p] = s; s += lcnt[p]; }
        loff[nparts] = s;
    }
    __syncthreads();
    if (t < nparts) gbase[t] = atomicAdd(&cur[t], lcnt[t]);
    __syncthreads();

#pragma unroll
    for (int i = 0; i < 4; i++) {
        if (bks[i] < 0) continue;
        int r = base + i * 256 + t;
        int p = bks[i] >> SH;
        int s = loff[p] + rnk[i];
        sid[s] = (uint32_t)bks[i];
        const float4* e = (const float4*)(emb + (size_t)r * 16);
        float4 A = e[0], B = e[1], C = e[2], D = e[3];
        uint32_t* d = &spay[s * 8];
        d[0] = pk2(A.x, A.y); d[1] = pk2(A.z, A.w);
        d[2] = pk2(B.x, B.y); d[3] = pk2(B.z, B.w);
        d[4] = pk2(C.x, C.y); d[5] = pk2(C.z, C.w);
        d[6] = pk2(D.x, D.y); d[7] = pk2(D.z, D.w);
    }
    __syncthreads();

    const int E = loff[nparts];
    for (int s = t; s < E; s += 256) {
        int b = (int)sid[s];
        int p = b >> SH;
        int dest = gbase[p] + (s - loff[p]);
        if (dest < cap) pid[(size_t)p * cap + dest] = (uint32_t)b;
        else atomicAdd(&ovfcnt[b + wofs], 1);
    }
    for (int j = t; j < E * 8; j += 256) {
        int s = j >> 3, q = j & 7;
        int b = (int)sid[s];
        int p = b >> SH;
        int dest = gbase[p] + (s - loff[p]);
        uint32_t x = spay[j];
        if (dest < cap) {
            pdata[((size_t)p * cap + dest) * 8 + q] = x;
        } else {
            atomicAdd(&ovf[(size_t)(b + wofs) * 16 + q * 2],     bfu2f(x & 0xffffu));
            atomicAdd(&ovf[(size_t)(b + wofs) * 16 + q * 2 + 1], bfu2f(x >> 16));
        }
    }
}

// Pass B: one block per (partition, CHUNK of entries). Prefetched sequential
// read, LDS segment-sum, coalesced partial write. ~574 active blocks.
__global__ __launch_bounds__(256) void partB_kernel(const uint32_t* __restrict__ pid0,
                                                    const uint32_t* __restrict__ pdata0,
                                                    const uint32_t* __restrict__ pid1,
                                                    const uint32_t* __restrict__ pdata1,
                                                    const int* __restrict__ curs,
                                                    float* __restrict__ partials,
                                                    int cap0, int cap1,
                                                    int nc0, int nc1) {
    const int bid = blockIdx.x;
    const bool is0 = bid < NP0 * nc0;
    int lp, ck;
    if (is0) { lp = bid / nc0; ck = bid % nc0; }
    else     { int r = bid - NP0 * nc0; lp = r / nc1; ck = r % nc1; }
    const int SH = is0 ? SH0T : SH1T;
    const int NBK = 1 << SH;
    const int p = is0 ? lp : NP0 + lp;
    const int cap = is0 ? cap0 : cap1;
    const uint32_t* pi = (is0 ? pid0 : pid1) + (size_t)lp * cap;
    const uint32_t* pd = (is0 ? pdata0 : pdata1) + (size_t)lp * cap * 8;
    int n = curs[p];
    if (n > cap) n = cap;
    const int start = ck * CHUNK;
    if (start >= n) return;                        // inactive chunk: never read
    const int end = (start + CHUNK < n) ? start + CHUNK : n;
    const int fb = lp << SH;

    __shared__ float sums[512 * 16];               // 32 KB
    __shared__ int cnt[512];
    const int t = threadIdx.x;
    for (int i = t; i < NBK * 16; i += 256) sums[i] = 0.0f;
    for (int i = t; i < NBK; i += 256) cnt[i] = 0;
    __syncthreads();

    const int q = t & 7;
    int j = start * 8 + t;
    const int e8 = end * 8;
    uint32_t x = 0; int lb = 0;
    bool v = j < e8;
    if (v) { x = pd[j]; lb = (int)pi[j >> 3] - fb; }
    while (v) {
        int jn = j + 256;
        bool vn = jn < e8;
        uint32_t xn = 0; int lbn = 0;
        if (vn) { xn = pd[jn]; lbn = (int)pi[jn >> 3] - fb; }   // prefetch next
        atomicAdd(&sums[lb * 16 + q * 2],     bfu2f(x & 0xffffu));
        atomicAdd(&sums[lb * 16 + q * 2 + 1], bfu2f(x >> 16));
        if (q == 0) atomicAdd(&cnt[lb], 1);
        j = jn; x = xn; lb = lbn; v = vn;
    }
    __syncthreads();

    float* P = partials + (size_t)bid * PSTRIDE;
    for (int i = t; i < NBK * 16; i += 256) P[i] = sums[i];
    for (int i = t; i < NBK; i += 256) P[512 * 16 + i] = (float)cnt[i];
}

// Combine: one thread per (bucket, dim). Sum chunk partials + overflow,
// divide_no_nan, write fp32 means.
__global__ __launch_bounds__(256) void combine_kernel(const float* __restrict__ partials,
                                                      const int* __restrict__ curs,
                                                      const int* __restrict__ ovfcnt,
                                                      const float* __restrict__ ovf,
                                                      float* __restrict__ means,
                                                      int cap0, int cap1,
                                                      int nc0, int nc1) {
    int i = blockIdx.x * 256 + threadIdx.x;
    if (i >= NB * 16) return;
    int w = i >> 4, d = i & 15;
    const bool is0 = w < Q0;
    const int b = is0 ? w : w - Q0;
    const int lp = b >> (is0 ? SH0T : SH1T);
    const int lb = b & (is0 ? 511 : 255);
    const int p = is0 ? lp : NP0 + lp;
    const int pb = is0 ? lp * nc0 : NP0 * nc0 + lp * nc1;
    const int cap = is0 ? cap0 : cap1;
    int n = curs[p];
    if (n > cap) n = cap;
    const int nc = (n + CHUNK - 1) / CHUNK;
    float s = 0.0f, c = 0.0f;
    for (int k = 0; k < nc; k++) {
        const float* P = partials + (size_t)(pb + k) * PSTRIDE;
        s += P[lb * 16 + d];
        c += P[512 * 16 + lb];
    }
    s += ovf[(size_t)w * 16 + d];
    c += (float)ovfcnt[w];
    means[(size_t)w * 16 + d] = (c > 0.0f) ? (s / c) : 0.0f;   // divide_no_nan
}

// Fused gather + 3-layer MLP using bf16 MFMA. One wave = one 16-row tile.
__global__ __launch_bounds__(256, 2) void mlp_mfma_kernel(
    const float* __restrict__ X, const int* __restrict__ z0, const int* __restrict__ z1,
    const float* __restrict__ means,
    const float* __restrict__ W1, const float* __restrict__ b1,
    const float* __restrict__ W2, const float* __restrict__ b2,
    const float* __restrict__ Wout, const float* __restrict__ bout,
    float* __restrict__ out)
{
    __shared__ float h1s[4][16 * 128];        // per-wave private transpose buffer (8 KB each)
    const int lane = threadIdx.x & 63;
    const int wv = threadIdx.x >> 6;
    const int c = lane & 15;                  // A-row / B-col / D-col index
    const int g = lane >> 4;                  // k-group
    float* h1w = h1s[wv];

    bf16x8 w1f[8][2];
#pragma unroll
    for (int ct = 0; ct < 8; ct++)
#pragma unroll
        for (int ks = 0; ks < 2; ks++)
#pragma unroll
            for (int e = 0; e < 8; e++)
                w1f[ct][ks][e] = f2bf(W1[(ks * 32 + g * 8 + e) * 128 + ct * 16 + c]);

    bf16x8 w2f[4][4];
#pragma unroll
    for (int ct = 0; ct < 4; ct++)
#pragma unroll
        for (int ks = 0; ks < 4; ks++)
#pragma unroll
            for (int e = 0; e < 8; e++)
                w2f[ct][ks][e] = f2bf(W2[(ks * 32 + g * 8 + e) * 64 + ct * 16 + c]);

    float b1v[8], b2v[4], wo[4];
#pragma unroll
    for (int ct = 0; ct < 8; ct++) b1v[ct] = b1[ct * 16 + c];
#pragma unroll
    for (int ct = 0; ct < 4; ct++) b2v[ct] = b2[ct * 16 + c];
#pragma unroll
    for (int t = 0; t < 4; t++) wo[t] = Wout[t * 16 + c];
    const float bo = bout[0];

    const int gg = g * 8;
    const bool is0 = (gg < 16);
    const int* zp = is0 ? z0 : z1;
    const size_t moff = is0 ? 0 : (size_t)Q0 * 16;
    const int esub = gg & 8;

    int waddr[4];
#pragma unroll
    for (int r = 0; r < 4; r++) {
        int rowl = g * 4 + r;
        waddr[r] = rowl * 128 + (c ^ ((rowl & 3) << 2));
    }
    const int xr = (c & 3) << 2;
    const int lo0 = ((g & 1) << 3) ^ xr;
    const int rbase0 = c * 128 + ((g >> 1) << 4) + lo0;
    const int rbase1 = c * 128 + ((g >> 1) << 4) + (lo0 ^ 4);

    const int wave_id = blockIdx.x * 4 + wv;
    const int nw = gridDim.x * 4;

    for (int tile = wave_id; tile < NTILES; tile += nw) {
        const int row = tile * 16 + c;

        bf16x8 a1[2];
        const float4* xp = (const float4*)(X + (size_t)row * 32 + gg);
        float4 x0 = xp[0], x1 = xp[1];
        a1[0][0] = f2bf(x0.x); a1[0][1] = f2bf(x0.y);
        a1[0][2] = f2bf(x0.z); a1[0][3] = f2bf(x0.w);
        a1[0][4] = f2bf(x1.x); a1[0][5] = f2bf(x1.y);
        a1[0][6] = f2bf(x1.z); a1[0][7] = f2bf(x1.w);

        int a = zp[row];
        const float4* ep = (const float4*)(means + moff + (size_t)a * 16 + esub);
        float4 e0 = ep[0], e1 = ep[1];
        a1[1][0] = f2bf(e0.x); a1[1][1] = f2bf(e0.y);
        a1[1][2] = f2bf(e0.z); a1[1][3] = f2bf(e0.w);
        a1[1][4] = f2bf(e1.x); a1[1][5] = f2bf(e1.y);
        a1[1][6] = f2bf(e1.z); a1[1][7] = f2bf(e1.w);

        f32x4 d1[8];
#pragma unroll
        for (int ct = 0; ct < 8; ct++) {
            f32x4 acc = {b1v[ct], b1v[ct], b1v[ct], b1v[ct]};
            acc = __builtin_amdgcn_mfma_f32_16x16x32_bf16(a1[0], w1f[ct][0], acc, 0, 0, 0);
            acc = __builtin_amdgcn_mfma_f32_16x16x32_bf16(a1[1], w1f[ct][1], acc, 0, 0, 0);
            d1[ct] = acc;
        }

#pragma unroll
        for (int ct = 0; ct < 8; ct++)
#pragma unroll
            for (int r = 0; r < 4; r++)
                h1w[waddr[r] + ct * 16] = fmaxf(d1[ct][r], 0.0f);

        bf16x8 a2[4];
#pragma unroll
        for (int ks = 0; ks < 4; ks++) {
            f32x4 p0 = *(const f32x4*)&h1w[rbase0 + ks * 32];
            f32x4 p1 = *(const f32x4*)&h1w[rbase1 + ks * 32];
            a2[ks][0] = f2bf(p0[0]); a2[ks][1] = f2bf(p0[1]);
            a2[ks][2] = f2bf(p0[2]); a2[ks][3] = f2bf(p0[3]);
            a2[ks][4] = f2bf(p1[0]); a2[ks][5] = f2bf(p1[1]);
            a2[ks][6] = f2bf(p1[2]); a2[ks][7] = f2bf(p1[3]);
        }

        f32x4 d2[4];
#pragma unroll
        for (int ct = 0; ct < 4; ct++) {
            f32x4 acc = {b2v[ct], b2v[ct], b2v[ct], b2v[ct]};
#pragma unroll
            for (int ks = 0; ks < 4; ks++)
                acc = __builtin_amdgcn_mfma_f32_16x16x32_bf16(a2[ks], w2f[ct][ks], acc, 0, 0, 0);
            d2[ct] = acc;
        }

        float sr[4];
#pragma unroll
        for (int r = 0; r < 4; r++) {
            float s = 0.0f;
#pragma unroll
            for (int ct = 0; ct < 4; ct++)
                s = fmaf(fmaxf(d2[ct][r], 0.0f), wo[ct], s);
            sr[r] = s;
        }
#pragma unroll
        for (int m = 1; m <= 8; m <<= 1)
#pragma unroll
            for (int r = 0; r < 4; r++)
                sr[r] += __shfl_xor(sr[r], m);
        if (c == 0) {
            float4 o = {sr[0] + bo, sr[1] + bo, sr[2] + bo, sr[3] + bo};
            *(float4*)(out + tile * 16 + g * 4) = o;
        }
    }
}

extern "C" void kernel_launch(void* const* d_in, const int* in_sizes, int n_in,
                              void* d_out, int out_size, void* d_ws, size_t ws_size,
                              hipStream_t stream) {
    const float* X    = (const float*)d_in[0];
    const int*   z0   = (const int*)d_in[1];
    const int*   z1   = (const int*)d_in[2];
    const float* emb0 = (const float*)d_in[3];
    const float* emb1 = (const float*)d_in[4];
    const float* W1   = (const float*)d_in[5];
    const float* b1   = (const float*)d_in[6];
    const float* W2   = (const float*)d_in[7];
    const float* b2   = (const float*)d_in[8];
    const float* Wout = (const float*)d_in[9];
    const float* bout = (const float*)d_in[10];
    float* out = (float*)d_out;
    char* ws = (char*)d_ws;

    // fixed region: cursors + ovfcnt + ovf + means
    const size_t fixedB = (size_t)NPARTS * 4 + (size_t)NB * 4 + (size_t)NB * 64 * 2;
    // capacity ladder (deterministic host-side); overflow path keeps every rung correct
    const int c0s[4] = {6656, 5632, 5376, 0};
    const int c1s[4] = {14336, 13056, 12800, 0};
    int CAP0 = 0, CAP1 = 0, NC0 = 0, NC1 = 0, NBLK = 0;
    for (int i = 0; i < 4; i++) {
        int nc0 = (c0s[i] + CHUNK - 1) / CHUNK;
        int nc1 = (c1s[i] + CHUNK - 1) / CHUNK;
        int nblk = NP0 * nc0 + NP1 * nc1;
        size_t need = ((size_t)NP0 * c0s[i] + (size_t)NP1 * c1s[i]) * 36
                    + (size_t)nblk * PSTRIDE * 4 + fixedB;
        if (need <= ws_size) { CAP0 = c0s[i]; CAP1 = c1s[i]; NC0 = nc0; NC1 = nc1; NBLK = nblk; break; }
    }

    char* p = ws;
    uint32_t* pdata0 = (uint32_t*)p;  p += (size_t)NP0 * CAP0 * 32;
    uint32_t* pdata1 = (uint32_t*)p;  p += (size_t)NP1 * CAP1 * 32;
    uint32_t* pid0   = (uint32_t*)p;  p += (size_t)NP0 * CAP0 * 4;
    uint32_t* pid1   = (uint32_t*)p;  p += (size_t)NP1 * CAP1 * 4;
    float* partials  = (float*)p;     p += (size_t)NBLK * PSTRIDE * 4;
    uint32_t* zbase  = (uint32_t*)p;
    int* curs        = (int*)p;       p += (size_t)NPARTS * 4;
    int* ovfcnt      = (int*)p;       p += (size_t)NB * 4;
    float* ovf       = (float*)p;     p += (size_t)NB * 64;
    float* means     = (float*)p;

    const int zero_dwords = NPARTS + NB + NB * 16;
    zero_ws_kernel<<<1024, 256, 0, stream>>>(zbase, zero_dwords);
    partA_kernel<<<2 * T_TILES, 256, 0, stream>>>(z0, z1, emb0, emb1,
                                                  pid0, pdata0, pid1, pdata1,
                                                  curs, ovfcnt, ovf, CAP0, CAP1);
    if (NBLK > 0) {
        partB_kernel<<<NBLK, 256, 0, stream>>>(pid0, pdata0, pid1, pdata1,
                                               curs, partials, CAP0, CAP1, NC0, NC1);
        combine_kernel<<<(NB * 16 + 255) / 256, 256, 0, stream>>>(partials, curs, ovfcnt,
                                                                  ovf, means, CAP0, CAP1,
                                                                  NC0, NC1);
    } else {
        // no-workspace fallback: means = ovf/ovfcnt only (partA sent everything to ovf)
        combine_kernel<<<(NB * 16 + 255) / 256, 256, 0, stream>>>(partials, curs, ovfcnt,
                                                                  ovf, means, 0, 0, 0, 0);
    }
    mlp_mfma_kernel<<<512, 256, 0, stream>>>(X, z0, z1, means, W1, b1, W2, b2,
                                             Wout, bout, out);
}